// Round 9
// baseline (156.572 us; speedup 1.0000x reference)
//
#include <hip/hip_runtime.h>

// Round 15: R8 base + PRECOMPUTED vertex normals (separate kernel) staged
// via DMA. Removes the last strided/redundant load class from fused:
//   - normal_precompute: 1 thread/vertex, dense sequential load9(tp+9v)
//     (21 MB read, exactly once) -> normal_of -> nrm[3v] (7 MB write).
//   - fused: normals become a 4th coalesced global_load_lds region
//     (12 B/vertex vs 36, 3x fewer cache lines; no normal_of VALU, no
//     strided load9, no ds_writes in the normals path).
// Staging = 100% DMA (T2,R2,V,N) + per-thread t1/r1 load9 + 192 halo dwords.
// LDS 29.4 KB (same as R8 -> same occupancy ~40%).
//
// Wave-slot map (ws = it*4 + wv, 8 iters): 0..10 sT2m (<648) | 11..21 sR2m
// | 22..25 sVm (<250) | 26..29 sNm (<225).
// Bank audit: T2ROW=288==0 mod 32, reads at 9l (9 coprime 32) -> permutation,
// lanes l/l+32 2-way (free, m136). VROW/NROW=100==4 mod 32, reads 3l -> same.
//
// Energy collapse (verified absmax==0 rounds 1-14):
//   sum_pq coeff[p][q](Dp.Dq) = 3(|u|^2+|w|^2+u.w) + (|a|^2+|b|^2+a.b), H=1.
// Adjacency (verified): quad q=(i,j), f1=tri1=i*m+j, tri2=Q+i*m+j.
//   diag : f2=tri2(i,j):   u=t1r2-t2r2, w=t1r1-t2r0; n1=N[v01], n2=N[v10]
//   horiz: f2=tri2(i-1,j): u=t1r0-t2r0, w=t1r2-t2r1; n1=N[v00], n2=N[v01]
//   vert : f2=tri2(i,j-1): u=t1r0-t2r2, w=t1r1-t2r1; n1=N[v00], n2=N[v10]
// Vertex normals = normal_of(tp[vertex_id]) (reference semantics; verified).
// Clamp-garbage audit (all masked by i<m&&j<m, i>0, j>0 as in R8):
//   sNm row clamp gi=min(i0+r,n-1) at i0=760,r=8 -> row 767 feeds only i=m
//   quads (masked). Col j0+32 overrun reads next row col 0 (in-bounds; 3V-4
//   clamp at gi=n-1) -> feeds only j=m quads (masked). T2/V/halo clamps
//   identical to R8 (verified absmax 0).

#define BI 8
#define BJ 32
#define T2ROW 288     // tri2 row stride (72 chunks exactly)
#define VROW  100     // verts row stride (25 chunks; 99 data + 1 pad)
#define NROW  100     // normals row stride (25 chunks; 99 data + 1 pad)
#define T2_CH 648     // 9 rows * 72
#define V_CH  250     // 10 rows * 25
#define N_CH  225     // 9 rows * 25
#define HALO_CNT 192  // 2*9*9 face-halo + 10*3 vert-halo dwords
#define NRM_OFS 32768 // byte offset of nrm[] inside d_ws (partials < 32 KB)

struct __attribute__((aligned(4))) F4s { float a, b, c, d; };
struct F3 { float x, y, z; };
struct R9 { float v[9]; };

__device__ __forceinline__ R9 load9(const float* __restrict__ p) {
    R9 r;
    F4s u0 = *(const F4s*)p;
    F4s u1 = *(const F4s*)(p + 4);
    r.v[0] = u0.a; r.v[1] = u0.b; r.v[2] = u0.c; r.v[3] = u0.d;
    r.v[4] = u1.a; r.v[5] = u1.b; r.v[6] = u1.c; r.v[7] = u1.d;
    r.v[8] = p[8];
    return r;
}

__device__ __forceinline__ int imin(int a, int b) { return a < b ? a : b; }
__device__ __forceinline__ int imax(int a, int b) { return a > b ? a : b; }

__device__ __forceinline__ void gload_lds16(const float* gp, float* lp) {
    __builtin_amdgcn_global_load_lds(
        (const __attribute__((address_space(1))) void*)gp,
        (__attribute__((address_space(3))) void*)lp, 16, 0, 0);
}

__device__ __forceinline__ F3 normal_of(const R9& r) {
    float e1x = r.v[0] - r.v[3], e1y = r.v[1] - r.v[4], e1z = r.v[2] - r.v[5];
    float e2x = r.v[0] - r.v[6], e2y = r.v[1] - r.v[7], e2z = r.v[2] - r.v[8];
    float nx = e1y * e2z - e1z * e2y;
    float ny = e1z * e2x - e1x * e2z;
    float nz = e1x * e2y - e1y * e2x;
    float inv = 1.0f / sqrtf(nx * nx + ny * ny + nz * nz);
    F3 o; o.x = nx * inv; o.y = ny * inv; o.z = nz * inv; return o;
}

__device__ __forceinline__ float tri_area_p(const float* p, const float* q,
                                            const float* r) {
    float ax = q[0] - p[0], ay = q[1] - p[1], az = q[2] - p[2];
    float bx = r[0] - p[0], by = r[1] - p[1], bz = r[2] - p[2];
    float cx = ay * bz - az * by, cy = az * bx - ax * bz, cz = ax * by - ay * bx;
    return 0.5f * sqrtf(cx * cx + cy * cy + cz * cz);
}

__device__ __forceinline__ float edge_ew(const float* u1, const float* u2,
                                         const float* w1, const float* w2,
                                         const float* rA, const float* rB,
                                         const F3& n1, const F3& n2,
                                         const float* pa, const float* pb,
                                         float asum) {
    float ux = u1[0] - u2[0], uy = u1[1] - u2[1], uz = u1[2] - u2[2];
    float wx = w1[0] - w2[0], wy = w1[1] - w2[1], wz = w1[2] - w2[2];

    float d0 = rA[0] - rB[0], d1 = rA[1] - rB[1], d2 = rA[2] - rB[2];
    float d3 = rA[3] - rB[3], d4 = rA[4] - rB[4], d5 = rA[5] - rB[5];
    float d6 = rA[6] - rB[6], d7 = rA[7] - rB[7], d8 = rA[8] - rB[8];

    float ax = n1.x * d0 + n1.y * d3 + n1.z * d6;
    float ay = n1.x * d1 + n1.y * d4 + n1.z * d7;
    float az = n1.x * d2 + n1.y * d5 + n1.z * d8;
    float bx = n2.x * d0 + n2.y * d3 + n2.z * d6;
    float by = n2.x * d1 + n2.y * d4 + n2.z * d7;
    float bz = n2.x * d2 + n2.y * d5 + n2.z * d8;

    float uu = ux * ux + uy * uy + uz * uz;
    float ww = wx * wx + wy * wy + wz * wz;
    float uw = ux * wx + uy * wy + uz * wz;
    float aa = ax * ax + ay * ay + az * az;
    float bb = bx * bx + by * by + bz * bz;
    float ab = ax * bx + ay * by + az * bz;
    float energy = (3.0f * (uu + ww + uw) + (aa + bb + ab)) * (1.0f / 9.0f);

    float dx = pa[0] - pb[0], dy = pa[1] - pb[1], dz = pa[2] - pb[2];
    return energy * (dx * dx + dy * dy + dz * dz) / asum;
}

__global__ __launch_bounds__(256) void normal_precompute(
        const float* __restrict__ tp, float* __restrict__ nrm, int V) {
    int v = blockIdx.x * 256 + threadIdx.x;
    if (v < V) {
        F3 nm = normal_of(load9(tp + (size_t)9 * v));
        nrm[3 * v]     = nm.x;
        nrm[3 * v + 1] = nm.y;
        nrm[3 * v + 2] = nm.z;
    }
}

__global__ __launch_bounds__(256) void fused_kernel(
        const float* __restrict__ tp,    // (2Q,3,3)
        const float* __restrict__ rot,   // (2Q,3,3)
        const float* __restrict__ verts, // (n*n,3)
        const float* __restrict__ nrm,   // (n*n,3) precomputed
        double* __restrict__ partials,
        int n) {
    const int m = n - 1;
    const int Q = m * m;
    const int F = 2 * Q;
    const int V = n * n;
    const int tid = threadIdx.x;
    const int i0 = blockIdx.y * BI;
    const int j0 = blockIdx.x * BJ;
    const int w = tid >> 5;          // row within tile, 0..7
    const int l = tid & 31;          // col within tile, 0..31
    const int i = i0 + w;
    const int j = j0 + l;
    const int wv = tid >> 6;         // wave64 id, 0..3
    const int lane = tid & 63;

    __shared__ __attribute__((aligned(16))) float sT2m[9 * T2ROW];
    __shared__ __attribute__((aligned(16))) float sR2m[9 * T2ROW];
    __shared__ __attribute__((aligned(16))) float sVm[10 * VROW];
    __shared__ __attribute__((aligned(16))) float sNm[9 * NROW];
    __shared__ float sT2h[9 * 12];
    __shared__ float sR2h[9 * 12];
    __shared__ float sVh[10 * 4];
    __shared__ double sred[4];

    // ---- (1) t1/r1 direct register loads, issued first ----
    int f1 = imin(i, m - 1) * m + imin(j, m - 1);
    R9 t1 = load9(tp  + (size_t)9 * f1);
    R9 r1 = load9(rot + (size_t)9 * f1);

    // ---- (2) main staging: all-DMA, wave-slot per region ----
#pragma unroll
    for (int it = 0; it < 8; ++it) {
        int ws = it * 4 + wv;                 // wave-uniform slot id, 0..31
        if (ws < 22) {
            int a = ws >= 11;                 // wave-uniform
            int wl = a ? ws - 11 : ws;
            int chunk = wl * 64 + lane;       // lane-linear
            if (chunk < T2_CH) {
                int r = chunk / 72, c = chunk - r * 72;
                int gi = imin(i0 - 1 + r, m - 1);   // can be -1: face idx >=0
                int g = 9 * (Q + gi * m + j0) + 4 * c;
                g = imin(g, 9 * F - 4);
                gload_lds16((a ? rot : tp) + g,
                            (a ? sR2m : sT2m) + chunk * 4);
            }
        } else if (ws < 26) {
            int chunk = (ws - 22) * 64 + lane;
            if (chunk < V_CH) {
                int r = chunk / 25, c = chunk - r * 25;
                int vr = imax(imin(i0 - 1 + r, n - 1), 0);
                int g = 3 * (vr * n + j0) + 4 * c;
                g = imin(g, 3 * V - 4);
                gload_lds16(verts + g, sVm + chunk * 4);
            }
        } else if (ws < 30) {
            int chunk = (ws - 26) * 64 + lane;
            if (chunk < N_CH) {
                int r = chunk / 25, c = chunk - r * 25;
                int gi = imin(i0 + r, n - 1);        // rows i0..i0+8
                int g = 3 * (gi * n + j0) + 4 * c;
                g = imin(g, 3 * V - 4);
                gload_lds16(nrm + g, sNm + chunk * 4);
            }
        }
    }

    // ---- (3) halo scalar loads (left column j0-1) ----
    float hval = 0.0f;
    float* hdst = nullptr;
    if (tid < HALO_CNT) {
        if (tid < 162) {
            int a = tid >= 81;
            int t = a ? tid - 81 : tid;
            int r = t / 9, k = t - 9 * r;
            int gi = imin(i0 - 1 + r, m - 1);
            int face = Q + gi * m + (j0 - 1);       // >= Q-m-1 >= 0, < F
            hval = (a ? rot : tp)[9 * face + k];
            hdst = (a ? sR2h : sT2h) + r * 12 + k;
        } else {
            int t = tid - 162;
            int r = t / 3, k = t - 3 * r;
            int vr = imax(imin(i0 - 1 + r, n - 1), 0);
            int g = imax(3 * (vr * n + (j0 - 1)) + k, 0);
            hval = verts[g];
            hdst = sVh + r * 4 + k;
        }
    }
    if (hdst) *hdst = hval;

    __syncthreads();   // drains DMA vmcnt + lgkmcnt

    // ---- (4) compute ----
    double term = 0.0;
    if (i < m && j < m) {
        const float* t2c = sT2m + (w + 1) * T2ROW + 9 * l;
        const float* r2c = sR2m + (w + 1) * T2ROW + 9 * l;
        const float* th  = sT2m + w * T2ROW + 9 * l;
        const float* rh  = sR2m + w * T2ROW + 9 * l;
        const float* tv  = l ? sT2m + (w + 1) * T2ROW + 9 * (l - 1)
                             : sT2h + (w + 1) * 12;
        const float* rv  = l ? sR2m + (w + 1) * T2ROW + 9 * (l - 1)
                             : sR2h + (w + 1) * 12;

        const float* p00 = sVm + (w + 1) * VROW + 3 * l;
        const float* p01 = p00 + 3;
        const float* p10 = sVm + (w + 2) * VROW + 3 * l;
        const float* p11 = p10 + 3;
        const float* pup = sVm + w * VROW + 3 * (l + 1);
        const float* plf = l ? sVm + (w + 2) * VROW + 3 * (l - 1)
                             : sVh + (w + 2) * 4;

        const float* na = sNm + w * NROW + 3 * l;
        const float* nb = na + 3;
        const float* nc = sNm + (w + 1) * NROW + 3 * l;
        F3 nA = { na[0], na[1], na[2] };
        F3 nB = { nb[0], nb[1], nb[2] };
        F3 nC = { nc[0], nc[1], nc[2] };

        float a1   = tri_area_p(p00, p10, p01);
        float a2c  = tri_area_p(p10, p11, p01);
        float a2up = tri_area_p(p00, p01, pup);
        float a2lf = tri_area_p(plf, p10, p00);

        float sum = edge_ew(t1.v + 6, t2c + 6, t1.v + 3, t2c + 0, r1.v, r2c,
                            nB, nC, p01, p10, a1 + a2c);
        float eh = edge_ew(t1.v + 0, th + 0, t1.v + 6, th + 3, r1.v, rh,
                           nA, nB, p00, p01, a1 + a2up);
        float ev = edge_ew(t1.v + 0, tv + 6, t1.v + 3, tv + 3, r1.v, rv,
                           nA, nC, p00, p10, a1 + a2lf);
        sum += (i > 0 ? eh : 0.0f);
        sum += (j > 0 ? ev : 0.0f);
        term = (double)sum;
    }

    // ---- (5) block reduction ----
#pragma unroll
    for (int off = 32; off > 0; off >>= 1) term += __shfl_down(term, off, 64);
    if (lane == 0) sred[wv] = term;
    __syncthreads();
    if (tid == 0)
        partials[blockIdx.y * gridDim.x + blockIdx.x] =
            sred[0] + sred[1] + sred[2] + sred[3];
}

__global__ __launch_bounds__(256) void finalize_kernel(
        const double* __restrict__ partials, int P, float* __restrict__ out) {
    double s = 0.0;
    for (int i = threadIdx.x; i < P; i += 256) s += partials[i];
#pragma unroll
    for (int off = 32; off > 0; off >>= 1) s += __shfl_down(s, off, 64);
    __shared__ double sred[4];
    int lane = threadIdx.x & 63, wid = threadIdx.x >> 6;
    if (lane == 0) sred[wid] = s;
    __syncthreads();
    if (threadIdx.x == 0) out[0] = (float)(sred[0] + sred[1] + sred[2] + sred[3]);
}

extern "C" void kernel_launch(void* const* d_in, const int* in_sizes, int n_in,
                              void* d_out, int out_size, void* d_ws, size_t ws_size,
                              hipStream_t stream) {
    const float* tp    = (const float*)d_in[0];
    const float* rot   = (const float*)d_in[1];
    const float* verts = (const float*)d_in[2];

    int V = in_sizes[2] / 3;
    int n = (int)(sqrtf((float)V) + 0.5f);
    int m = n - 1;

    double* partials = (double*)d_ws;
    float*  nrm      = (float*)((char*)d_ws + NRM_OFS);
    float*  out      = (float*)d_out;

    normal_precompute<<<(V + 255) / 256, 256, 0, stream>>>(tp, nrm, V);

    dim3 grid((m + BJ - 1) / BJ, (m + BI - 1) / BI);
    int P = grid.x * grid.y;
    fused_kernel<<<grid, 256, 0, stream>>>(tp, rot, verts, nrm, partials, n);
    finalize_kernel<<<1, 256, 0, stream>>>(partials, P, out);
}